// Round 1
// 268.887 us; speedup vs baseline: 1.1679x; 1.1679x over previous
//
#include <hip/hip_runtime.h>
#include <cstdint>
#include <cstddef>

typedef unsigned short u16;
typedef __bf16 bf16_t;
typedef bf16_t bf16x8 __attribute__((ext_vector_type(8)));
typedef float f32x4 __attribute__((ext_vector_type(4)));

__device__ __forceinline__ u16 f32_to_bf16(float f) {
  uint32_t u = __builtin_bit_cast(uint32_t, f);
  u += 0x7fffu + ((u >> 16) & 1u);   // RNE
  return (u16)(u >> 16);
}

// pack two f32 -> two bf16 in one u32 (round-half-up + v_perm_b32)
__device__ __forceinline__ uint32_t pack_bf16x2(float lo, float hi) {
  uint32_t a = __builtin_bit_cast(uint32_t, hi) + 0x8000u;
  uint32_t b = __builtin_bit_cast(uint32_t, lo) + 0x8000u;
  return __builtin_amdgcn_perm(a, b, 0x07060302u);
}

// async global->LDS, 16B per lane. LDS dest is wave-uniform base; HW adds lane*16.
__device__ __forceinline__ void gload_lds16(const void* g, void* l) {
  __builtin_amdgcn_global_load_lds(
      (const __attribute__((address_space(1))) unsigned int*)g,
      (__attribute__((address_space(3))) unsigned int*)l, 16, 0, 0);
}

// ---------------- fp32 -> bf16 elementwise convert ----------------
__global__ void cvt_bf16(const float* __restrict__ in, u16* __restrict__ out, int n) {
  int i = (blockIdx.x * 256 + threadIdx.x) * 4;
  if (i < n) {
    float4 f = *(const float4*)(in + i);
    ushort4 o;
    o.x = f32_to_bf16(f.x); o.y = f32_to_bf16(f.y);
    o.z = f32_to_bf16(f.z); o.w = f32_to_bf16(f.w);
    *(ushort4*)(out + i) = o;
  }
}

// ---------------- fp32 [R][C] -> bf16 [C][R] transpose-convert ----------------
__global__ void tconv(const float* __restrict__ in, u16* __restrict__ out, int R, int C) {
  __shared__ u16 t[64][80];
  int tid = threadIdx.x;
  int cb = blockIdx.x * 64, rb = blockIdx.y * 64;
  int rr = tid >> 2, cg = (tid & 3) * 16;
  const float* ip = in + (size_t)(rb + rr) * C + cb + cg;
#pragma unroll
  for (int i = 0; i < 16; ++i) t[rr][cg + i] = f32_to_bf16(ip[i]);
  __syncthreads();
  int cc = tid >> 2, rg = (tid & 3) * 16;
  u16* op = out + (size_t)(cb + cc) * R + rb + rg;
  union { uint4 v[2]; u16 s[16]; } tmp;
#pragma unroll
  for (int i = 0; i < 16; ++i) tmp.s[i] = t[rg + i][cc];
  *(uint4*)op = tmp.v[0];
  *(uint4*)(op + 8) = tmp.v[1];
}

// ---------------- V slice of qkv (bf16) -> Vt [bh][d=64][t=2048] ----------------
__global__ void vtrans(const u16* __restrict__ qkvb, u16* __restrict__ vt) {
  __shared__ u16 t[64][80];
  int tid = threadIdx.x;
  int bh = blockIdx.x, tb = blockIdx.y * 64;
  int b = bh >> 4, h = bh & 15;
  int tt = tid >> 2, dg = (tid & 3) * 16;
  const u16* ip = qkvb + (size_t)(b * 2048 + tb + tt) * 3072 + 2048 + h * 64 + dg;
  union { uint4 v; u16 s[8]; } a0, a1;
  a0.v = *(const uint4*)ip;
  a1.v = *(const uint4*)(ip + 8);
#pragma unroll
  for (int i = 0; i < 8; ++i) { t[tt][dg + i] = a0.s[i]; t[tt][dg + 8 + i] = a1.s[i]; }
  __syncthreads();
  int dd = tid >> 2, tg = (tid & 3) * 16;
  u16* op = vt + (size_t)(bh * 64 + dd) * 2048 + tb + tg;
  union { uint4 v[2]; u16 s[16]; } tmp;
#pragma unroll
  for (int i = 0; i < 16; ++i) tmp.s[i] = t[tg + i][dd];
  *(uint4*)op = tmp.v[0];
  *(uint4*)(op + 8) = tmp.v[1];
}

// ---------------- 256x256 8-phase bf16 GEMM: C[M,N] = A[M,K]*Bt[N,K]^T + bias --
// Template (learn_hip m201): BM=BN=256, BK=64, 8 waves (2M x 4N), per-wave out
// 128x64. LDS 128 KiB: [buf][A|B][256 rows x 64 k x bf16], double-buffered per
// K-tile. Staging: global_load_lds dwordx4, linear LDS dest; k-granule (16B)
// XOR-swizzled on the GLOBAL source (g ^= row&7), same XOR on ds_read side ->
// conflict-free reads. 8 phases / 2 K-tiles; counted vmcnt(6) at phases 4/8
// only (3 quarter-pairs in flight across barriers); raw s_barrier (no vm drain);
// setprio(1) around each 16-MFMA cluster. Tail stages clamp kt -> uniform
// vmcnt counts, write only dead regions.
template <int OUT_BF16>
__global__ __launch_bounds__(512, 2) void gemm256(const u16* __restrict__ A,
                                                  const u16* __restrict__ Bt,
                                                  const float* __restrict__ bias,
                                                  void* __restrict__ Cout,
                                                  int M, int N, int K) {
  __shared__ __align__(16) u16 lds[2][2][16384];  // [buf][0=A,1=B][256*64]
  const int tid = threadIdx.x;
  const int w = tid >> 6, L = tid & 63;
  const int quad = L >> 4, lc = L & 15;
  const int wr = w >> 2, wc = w & 3;          // 2 M-waves x 4 N-waves
  const int wrM = wr * 128, wcN = wc * 64;
  const int rL = L >> 3;                       // row within a wave's 8-row chunk
  const int gsw = (L & 7) ^ rL;                // pre-swizzled source granule

  // XCD-aware bijective block swizzle (gridDim.x % 8 == 0 for both launches)
  const int nbx = N >> 8;
  const int cpx = gridDim.x >> 3;
  const int id = blockIdx.x;
  const int swz = (id & 7) * cpx + (id >> 3);
  const int tileN = (swz % nbx) << 8;
  const int tileM = (swz / nbx) << 8;
  const int nkt = K >> 6;

  u16* const A0 = &lds[0][0][0];
  u16* const B0 = &lds[0][1][0];
  u16* const A1 = &lds[1][0][0];
  u16* const B1 = &lds[1][1][0];

  // stage one 64-row quarter (8 rows per wave, 16B per lane, linear LDS dest)
  auto stageQ = [&](const u16* Mp, int gRow, int kt, u16* reg) {
    int ktc = kt < nkt ? kt : nkt - 1;  // clamped tail: region-safe, count-safe
    const u16* src = Mp + (size_t)(gRow + w * 8 + rL) * K + (ktc << 6) + gsw * 8;
    gload_lds16(src, reg + w * 512);
  };

  f32x4 acc[8][4] = {};
  const int rsw = lc & 7;
  const int g0 = (quad ^ rsw) * 8;        // swizzled ds_read granule, ks=0
  const int g1 = ((4 + quad) ^ rsw) * 8;  // ks=1
  const int aRow = (wrM + lc) * 64;
  const int bRow = (wcN + lc) * 64;

  // ---- prologue: tile0 (8 quarters) + tile1 (6 quarters; B-hi comes at ph1)
  stageQ(A, tileM + 0, 0, A0 + 0);
  stageQ(A, tileM + 128, 0, A0 + 8192);
  stageQ(Bt, tileN + 0, 0, B0 + 0);
  stageQ(Bt, tileN + 64, 0, B0 + 4096);
  stageQ(A, tileM + 64, 0, A0 + 4096);
  stageQ(A, tileM + 192, 0, A0 + 12288);
  stageQ(Bt, tileN + 128, 0, B0 + 8192);
  stageQ(Bt, tileN + 192, 0, B0 + 12288);
  stageQ(A, tileM + 0, 1, A1 + 0);
  stageQ(A, tileM + 128, 1, A1 + 8192);
  stageQ(Bt, tileN + 0, 1, B1 + 0);
  stageQ(Bt, tileN + 64, 1, B1 + 4096);
  stageQ(A, tileM + 64, 1, A1 + 4096);
  stageQ(A, tileM + 192, 1, A1 + 12288);
  asm volatile("s_waitcnt vmcnt(6)" ::: "memory");  // tile0 resident
  __builtin_amdgcn_s_barrier();

  // ---- one 4-phase group: compute K-tile T from (Ab,Bb); prefetch
  //      B-hi(T+1)->Bob at ph1, tile(T+2)->(Ab,Bb) at ph2/3/4.
  auto group = [&](u16* Ab, u16* Bb, u16* Bob, int T) {
    bf16x8 af[4][2], blo[2][2], bhi[2][2];
    // ph1: read A-lo + B-lo; stage B r2,r3 of T+1 (other buf)
#pragma unroll
    for (int mi = 0; mi < 4; ++mi) {
      af[mi][0] = *(const bf16x8*)&Ab[aRow + mi * 1024 + g0];
      af[mi][1] = *(const bf16x8*)&Ab[aRow + mi * 1024 + g1];
    }
#pragma unroll
    for (int ni = 0; ni < 2; ++ni) {
      blo[ni][0] = *(const bf16x8*)&Bb[bRow + ni * 1024 + g0];
      blo[ni][1] = *(const bf16x8*)&Bb[bRow + ni * 1024 + g1];
    }
    stageQ(Bt, tileN + 128, T + 1, Bob + 8192);
    stageQ(Bt, tileN + 192, T + 1, Bob + 12288);
    asm volatile("" ::: "memory");
    __builtin_amdgcn_s_barrier();
    asm volatile("s_waitcnt lgkmcnt(0)" ::: "memory");
    __builtin_amdgcn_s_setprio(1);
#pragma unroll
    for (int mi = 0; mi < 4; ++mi)
#pragma unroll
      for (int ni = 0; ni < 2; ++ni) {
        acc[mi][ni] = __builtin_amdgcn_mfma_f32_16x16x32_bf16(af[mi][0], blo[ni][0], acc[mi][ni], 0, 0, 0);
        acc[mi][ni] = __builtin_amdgcn_mfma_f32_16x16x32_bf16(af[mi][1], blo[ni][1], acc[mi][ni], 0, 0, 0);
      }
    __builtin_amdgcn_s_setprio(0);
    asm volatile("" ::: "memory");
    __builtin_amdgcn_s_barrier();
    // ph2: read B-hi; stage A q0,q2 of T+2 (freed by ph1 reads)
#pragma unroll
    for (int ni = 0; ni < 2; ++ni) {
      bhi[ni][0] = *(const bf16x8*)&Bb[bRow + (2 + ni) * 1024 + g0];
      bhi[ni][1] = *(const bf16x8*)&Bb[bRow + (2 + ni) * 1024 + g1];
    }
    stageQ(A, tileM + 0, T + 2, Ab + 0);
    stageQ(A, tileM + 128, T + 2, Ab + 8192);
    asm volatile("" ::: "memory");
    __builtin_amdgcn_s_barrier();
    asm volatile("s_waitcnt lgkmcnt(0)" ::: "memory");
    __builtin_amdgcn_s_setprio(1);
#pragma unroll
    for (int mi = 0; mi < 4; ++mi)
#pragma unroll
      for (int ni = 0; ni < 2; ++ni) {
        acc[mi][ni + 2] = __builtin_amdgcn_mfma_f32_16x16x32_bf16(af[mi][0], bhi[ni][0], acc[mi][ni + 2], 0, 0, 0);
        acc[mi][ni + 2] = __builtin_amdgcn_mfma_f32_16x16x32_bf16(af[mi][1], bhi[ni][1], acc[mi][ni + 2], 0, 0, 0);
      }
    __builtin_amdgcn_s_setprio(0);
    asm volatile("" ::: "memory");
    __builtin_amdgcn_s_barrier();
    // ph3: read A-hi; stage B r0,r1 of T+2 (freed by ph2 reads)
#pragma unroll
    for (int mi = 0; mi < 4; ++mi) {
      af[mi][0] = *(const bf16x8*)&Ab[aRow + (4 + mi) * 1024 + g0];
      af[mi][1] = *(const bf16x8*)&Ab[aRow + (4 + mi) * 1024 + g1];
    }
    stageQ(Bt, tileN + 0, T + 2, Bb + 0);
    stageQ(Bt, tileN + 64, T + 2, Bb + 4096);
    asm volatile("" ::: "memory");
    __builtin_amdgcn_s_barrier();
    asm volatile("s_waitcnt lgkmcnt(0)" ::: "memory");
    __builtin_amdgcn_s_setprio(1);
#pragma unroll
    for (int mi = 0; mi < 4; ++mi)
#pragma unroll
      for (int ni = 0; ni < 2; ++ni) {
        acc[mi + 4][ni + 2] = __builtin_amdgcn_mfma_f32_16x16x32_bf16(af[mi][0], bhi[ni][0], acc[mi + 4][ni + 2], 0, 0, 0);
        acc[mi + 4][ni + 2] = __builtin_amdgcn_mfma_f32_16x16x32_bf16(af[mi][1], bhi[ni][1], acc[mi + 4][ni + 2], 0, 0, 0);
      }
    __builtin_amdgcn_s_setprio(0);
    asm volatile("" ::: "memory");
    __builtin_amdgcn_s_barrier();
    // ph4: no reads; stage A q1,q3 of T+2 (freed by ph3 reads); counted vmcnt
    stageQ(A, tileM + 64, T + 2, Ab + 4096);
    stageQ(A, tileM + 192, T + 2, Ab + 12288);
    asm volatile("" ::: "memory");
    __builtin_amdgcn_s_barrier();
    __builtin_amdgcn_s_setprio(1);
#pragma unroll
    for (int mi = 0; mi < 4; ++mi)
#pragma unroll
      for (int ni = 0; ni < 2; ++ni) {
        acc[mi + 4][ni] = __builtin_amdgcn_mfma_f32_16x16x32_bf16(af[mi][0], blo[ni][0], acc[mi + 4][ni], 0, 0, 0);
        acc[mi + 4][ni] = __builtin_amdgcn_mfma_f32_16x16x32_bf16(af[mi][1], blo[ni][1], acc[mi + 4][ni], 0, 0, 0);
      }
    __builtin_amdgcn_s_setprio(0);
    asm volatile("s_waitcnt vmcnt(6)" ::: "memory");  // next K-tile resident
    __builtin_amdgcn_s_barrier();
  };

  for (int T = 0; T < nkt; T += 2) {
    group(A0, B0, B1, T);
    group(A1, B1, B0, T + 1);
  }

  // drain in-flight LDS-DMA before this block's LDS can be reassigned
  asm volatile("s_waitcnt vmcnt(0)" ::: "memory");

#pragma unroll
  for (int mi = 0; mi < 8; ++mi) {
    int rowb = tileM + wrM + mi * 16 + quad * 4;
#pragma unroll
    for (int ni = 0; ni < 4; ++ni) {
      int col = tileN + wcN + ni * 16 + lc;
      float bv = bias[col];
#pragma unroll
      for (int r = 0; r < 4; ++r) {
        float v = acc[mi][ni][r] + bv;
        if (OUT_BF16)
          ((u16*)Cout)[(size_t)(rowb + r) * N + col] = f32_to_bf16(v);
        else
          ((float*)Cout)[(size_t)(rowb + r) * N + col] = v;
      }
    }
  }
}

// ---------------- causal flash attention, S^T formulation ----------------
// (unchanged this round)
__global__ __launch_bounds__(256, 4) void attn(const u16* __restrict__ qkvb,
                                               const u16* __restrict__ vt,
                                               u16* __restrict__ yb) {
  __shared__ __align__(16) u16 kbuf[8 * 512];
  __shared__ __align__(16) u16 vbuf[8 * 512];
  __shared__ __align__(16) u16 pbuf[4][1024];  // per-wave, frag order [ks][lane][8]
  const int tid = threadIdx.x;
  const int w = tid >> 6, L = tid & 63;
  const int quad = L >> 4, lc = L & 15;
  const int bh = blockIdx.x;
  const int b = bh >> 4, h = bh & 15;
  const int pair = blockIdx.y;
  const float e_c = 0.18033688f;  // (1/sqrt(64)) * log2(e)
  u16* pb = (u16*)pbuf[w];

  for (int pass = 0; pass < 2; ++pass) {
    const int qt = pass ? (31 - pair) : pair;
    const int qbase = qt * 64;
    const int q_loc = w * 16 + lc;

    bf16x8 qf[2];
    {
      const u16* qp = qkvb + ((size_t)(b * 2048 + qbase + q_loc) * 3072 + h * 64 + quad * 8);
      qf[0] = *(const bf16x8*)qp;
      qf[1] = *(const bf16x8*)(qp + 32);
    }
    f32x4 o[4] = {};
    float lsum = 0.f;

    for (int kb = 0; kb <= qbase; kb += 64) {
      const bool diag = (kb == qbase);
      __syncthreads();
#pragma unroll
      for (int i = 0; i < 4; ++i) {
        int fb = w * 4 + i;  // wave-uniform
        if (fb < 8) {        // K tile, A-operand of K·Q^T (m=tk, k=d)
          int nt = fb >> 1, ks = fb & 1;
          int tk = kb + nt * 16 + lc;
          int d = ks * 32 + quad * 8;
          gload_lds16(qkvb + ((size_t)(b * 2048 + tk) * 3072 + 1024 + h * 64 + d), &kbuf[fb * 512]);
        } else {             // V^T tile, A-operand of V^T·P (m=d, k=tk)
          int f = fb - 8;
          int dt = f >> 1, ks = f & 1;
          int d = dt * 16 + lc;
          int tk = kb + ks * 32 + quad * 8;
          gload_lds16(vt + ((size_t)(bh * 64 + d) * 2048 + tk), &vbuf[f * 512]);
        }
      }
      __syncthreads();

      // S^T[tk][q]
      f32x4 s[4];
#pragma unroll
      for (int nt = 0; nt < 4; ++nt) {
        s[nt] = (f32x4){0.f, 0.f, 0.f, 0.f};
#pragma unroll
        for (int ks = 0; ks < 2; ++ks) {
          bf16x8 kf = *(const bf16x8*)&kbuf[(nt * 2 + ks) * 512 + L * 8];
          s[nt] = __builtin_amdgcn_mfma_f32_16x16x32_bf16(kf, qf[ks], s[nt], 0, 0, 0);
        }
      }

      // p = exp2(s*e_c); mask diagonal; accumulate per-lane l; pack to pbuf
#pragma unroll
      for (int nt = 0; nt < 4; ++nt) {
        float p0 = __builtin_amdgcn_exp2f(s[nt][0] * e_c);
        float p1 = __builtin_amdgcn_exp2f(s[nt][1] * e_c);
        float p2 = __builtin_amdgcn_exp2f(s[nt][2] * e_c);
        float p3 = __builtin_amdgcn_exp2f(s[nt][3] * e_c);
        if (diag) {
          int tk0 = nt * 16 + quad * 4;
          p0 = (tk0 + 0 > q_loc) ? 0.f : p0;
          p1 = (tk0 + 1 > q_loc) ? 0.f : p1;
          p2 = (tk0 + 2 > q_loc) ? 0.f : p2;
          p3 = (tk0 + 3 > q_loc) ? 0.f : p3;
        }
        lsum += (p0 + p1) + (p2 + p3);
        uint2 pk;
        pk.x = pack_bf16x2(p0, p1);
        pk.y = pack_bf16x2(p2, p3);
        // frag slot: ks=nt>>1, lane'=((nt&1)*2+(quad>>1))*16+lc, j_base=(quad&1)*4
        int idx = (nt >> 1) * 512 + (((nt & 1) * 2 + (quad >> 1)) * 16 + lc) * 8 + (quad & 1) * 4;
        *(uint2*)&pb[idx] = pk;
      }

      // O^T += V^T · P
#pragma unroll
      for (int ks = 0; ks < 2; ++ks) {
        bf16x8 pf = *(const bf16x8*)&pb[ks * 512 + L * 8];
#pragma unroll
        for (int dt = 0; dt < 4; ++dt) {
          bf16x8 vf = *(const bf16x8*)&vbuf[(dt * 2 + ks) * 512 + L * 8];
          o[dt] = __builtin_amdgcn_mfma_f32_16x16x32_bf16(vf, pf, o[dt], 0, 0, 0);
        }
      }
    }

    // l: sum the 4 quad partials for column q=lc
    lsum += __shfl_xor(lsum, 16);
    lsum += __shfl_xor(lsum, 32);
    float inv = 1.f / lsum;

    // store y[t=qbase+q_loc][h*64 + d], lane holds d = dt*16 + quad*4 + r
    {
      u16* yp = yb + (size_t)(b * 2048 + qbase + q_loc) * 1024 + h * 64 + quad * 4;
#pragma unroll
      for (int dt = 0; dt < 4; ++dt) {
        uint2 pk;
        pk.x = pack_bf16x2(o[dt][0] * inv, o[dt][1] * inv);
        pk.y = pack_bf16x2(o[dt][2] * inv, o[dt][3] * inv);
        *(uint2*)(yp + dt * 16) = pk;
      }
    }
  }
}

extern "C" void kernel_launch(void* const* d_in, const int* in_sizes, int n_in,
                              void* d_out, int out_size, void* d_ws, size_t ws_size,
                              hipStream_t stream) {
  const float* x = (const float*)d_in[0];
  const float* w_attn = (const float*)d_in[1];
  const float* b_attn = (const float*)d_in[2];
  const float* w_proj = (const float*)d_in[3];
  const float* b_proj = (const float*)d_in[4];
  float* out = (float*)d_out;

  char* ws = (char*)d_ws;
  u16* xb = (u16*)ws;    ws += (size_t)8192 * 1024 * 2;
  u16* waT = (u16*)ws;   ws += (size_t)3072 * 1024 * 2;
  u16* wpT = (u16*)ws;   ws += (size_t)1024 * 1024 * 2;
  u16* qkvb = (u16*)ws;  ws += (size_t)8192 * 3072 * 2;
  u16* vtb = (u16*)ws;   ws += (size_t)64 * 64 * 2048 * 2;
  u16* yb = (u16*)ws;    ws += (size_t)8192 * 1024 * 2;

  cvt_bf16<<<8192, 256, 0, stream>>>(x, xb, 8192 * 1024);
  tconv<<<dim3(3072 / 64, 1024 / 64), 256, 0, stream>>>(w_attn, waT, 1024, 3072);
  tconv<<<dim3(1024 / 64, 1024 / 64), 256, 0, stream>>>(w_proj, wpT, 1024, 1024);
  // 256^2 tiles: QKV grid = (8192/256)*(3072/256) = 384 blocks (384%8==0)
  gemm256<1><<<dim3(384), 512, 0, stream>>>(xb, waT, b_attn, qkvb, 8192, 3072, 1024);
  vtrans<<<dim3(64, 32), 256, 0, stream>>>(qkvb, vtb);
  attn<<<dim3(64, 16), 256, 0, stream>>>(qkvb, vtb, yb);
  // proj grid = (8192/256)*(1024/256) = 128 blocks (128%8==0)
  gemm256<0><<<dim3(128), 512, 0, stream>>>(yb, wpT, b_proj, out, 8192, 1024, 1024);
}